// Round 1
// baseline (35498.691 us; speedup 1.0000x reference)
//
#include <hip/hip_runtime.h>
#include <hip/hip_bf16.h>
#include <math.h>

// Problem constants (from reference): T=256, B=64, I=512, H=512
#define T_LEN 256
#define BATCH 64
#define HSZ   512

// ws layout (floats):
//   h_buf0: [4][B][H]            = 131072
//   h_buf1: [4][B][H]            = 131072
//   c_state:[4][B][H]            = 131072
//   h1:     [T][B][2H]           = 16777216
// total = 17,170,432 floats = 68.7 MB

__device__ __forceinline__ float sigmoidf_(float x) {
    return 1.0f / (1.0f + __expf(-x));
}

__global__ void init_state(const float* __restrict__ h0, const float* __restrict__ c0,
                           float* __restrict__ h_buf0, float* __restrict__ c_state) {
    int i = blockIdx.x * blockDim.x + threadIdx.x;
    if (i < 4 * BATCH * HSZ) {
        h_buf0[i]  = h0[i];
        c_state[i] = c0[i];
    }
}

// One time step for one layer (both directions).
// DIN = 512 (layer0, zin = x) or 1024 (layer1, zin = h1).
// Grid: 128 blocks = cell_dir(2) x ublock(32) x bhalf(2); 256 threads.
// WG owns 16 hidden units (64 gate rows) x 32 batches.
// Thread: all 4 gates of one unit, for 2 batches (bg and bg+16).
template<int DIN>
__global__ __launch_bounds__(256)
void lstm_step(const float* __restrict__ zin,
               const int*   __restrict__ lengths,
               const float* __restrict__ wih_f, const float* __restrict__ whh_f,
               const float* __restrict__ bih_f, const float* __restrict__ bhh_f,
               const float* __restrict__ wih_b, const float* __restrict__ whh_b,
               const float* __restrict__ bih_b, const float* __restrict__ bhh_b,
               const float* __restrict__ h_read,
               float*       __restrict__ h_write,
               float*       __restrict__ c_state,
               float*       __restrict__ outp,   // (T,B,1024): h1 for layer0, out for layer1
               int s)
{
    constexpr int BASE_CELL = (DIN == 512) ? 0 : 2;
    constexpr int KTOT = DIN + HSZ;

    const int cell_dir = blockIdx.x & 1;           // 0 fwd, 1 bwd
    const int ub       = (blockIdx.x >> 1) & 31;   // unit block (16 units)
    const int bh       = blockIdx.x >> 6;          // batch half (32 batches)
    const int cell     = BASE_CELL + cell_dir;
    const int t        = cell_dir ? (T_LEN - 1 - s) : s;

    const float* wih = cell_dir ? wih_b : wih_f;
    const float* whh = cell_dir ? whh_b : whh_f;
    const float* bih = cell_dir ? bih_b : bih_f;
    const float* bhh = cell_dir ? bhh_b : bhh_f;

    const int tid = threadIdx.x;
    const int bg  = tid & 15;        // batch group 0..15
    const int ut  = tid >> 4;        // unit 0..15
    const int u   = ub * 16 + ut;    // hidden unit 0..511

    __shared__ float zs[32][68];     // [batch_local][k] stride 68 (16B-aligned rows, ~2-way reads)

    float acc[4][2];
#pragma unroll
    for (int g = 0; g < 4; ++g) { acc[g][0] = 0.f; acc[g][1] = 0.f; }

    // staging map: lb = tid>>3 (batch local 0..31), kq = tid&7 (two float4s at kq*8, kq*8+4)
    const int lb = tid >> 3;
    const int kq = tid & 7;
    const int bglob_stage = bh * 32 + lb;

    for (int kc = 0; kc < KTOT; kc += 64) {
        __syncthreads();
        // stage z chunk: z[k] = (k < DIN) ? zin[t,b,k] : h_read[cell,b,k-DIN]
#pragma unroll
        for (int hh = 0; hh < 2; ++hh) {
            int kg = kc + kq * 8 + 4 * hh;
            float4 v;
            if (kg < DIN) {
                v = *reinterpret_cast<const float4*>(&zin[((size_t)t * BATCH + bglob_stage) * DIN + kg]);
            } else {
                v = *reinterpret_cast<const float4*>(&h_read[((size_t)cell * BATCH + bglob_stage) * HSZ + (kg - DIN)]);
            }
            int kl = kq * 8 + 4 * hh;
            zs[lb][kl + 0] = v.x; zs[lb][kl + 1] = v.y; zs[lb][kl + 2] = v.z; zs[lb][kl + 3] = v.w;
        }
        __syncthreads();

        // weight source for this chunk (chunks never straddle the DIN boundary)
        const float* wb;
        int rstride;
        if (kc < DIN) { wb = wih + kc;         rstride = DIN; }
        else          { wb = whh + (kc - DIN); rstride = HSZ; }

#pragma unroll 4
        for (int k4 = 0; k4 < 16; ++k4) {
            float4 wv[4];
#pragma unroll
            for (int g = 0; g < 4; ++g) {
                wv[g] = *reinterpret_cast<const float4*>(&wb[(size_t)(g * 512 + u) * rstride + k4 * 4]);
            }
            float4 za[2];
            za[0] = *reinterpret_cast<const float4*>(&zs[bg][k4 * 4]);
            za[1] = *reinterpret_cast<const float4*>(&zs[bg + 16][k4 * 4]);
#pragma unroll
            for (int g = 0; g < 4; ++g) {
#pragma unroll
                for (int j = 0; j < 2; ++j) {
                    acc[g][j] += wv[g].x * za[j].x;
                    acc[g][j] += wv[g].y * za[j].y;
                    acc[g][j] += wv[g].z * za[j].z;
                    acc[g][j] += wv[g].w * za[j].w;
                }
            }
        }
    }

    // bias
    float bsum[4];
#pragma unroll
    for (int g = 0; g < 4; ++g) {
        int row = g * 512 + u;
        bsum[g] = bih[row] + bhh[row];
    }

#pragma unroll
    for (int j = 0; j < 2; ++j) {
        const int b = bh * 32 + bg + 16 * j;
        const float gi = sigmoidf_(acc[0][j] + bsum[0]);
        const float gf = sigmoidf_(acc[1][j] + bsum[1]);
        const float gg = tanhf(acc[2][j] + bsum[2]);
        const float go = sigmoidf_(acc[3][j] + bsum[3]);

        const size_t idx = ((size_t)cell * BATCH + b) * HSZ + u;
        const float cprev = c_state[idx];
        const float hprev = h_read[idx];
        const float cy = gf * cprev + gi * gg;
        const float hy = go * tanhf(cy);

        const bool m = (t < lengths[b]);
        c_state[idx] = m ? cy : cprev;
        h_write[idx] = m ? hy : hprev;
        outp[((size_t)t * BATCH + b) * 1024 + cell_dir * 512 + u] = m ? hy : 0.f;
    }
}

extern "C" void kernel_launch(void* const* d_in, const int* in_sizes, int n_in,
                              void* d_out, int out_size, void* d_ws, size_t ws_size,
                              hipStream_t stream) {
    const float* x        = (const float*)d_in[0];
    const int*   lengths  = (const int*)d_in[1];
    const float* h0       = (const float*)d_in[2];
    const float* c0       = (const float*)d_in[3];
    const float* w_ih_l0  = (const float*)d_in[4];
    const float* w_hh_l0  = (const float*)d_in[5];
    const float* b_ih_l0  = (const float*)d_in[6];
    const float* b_hh_l0  = (const float*)d_in[7];
    const float* w_ih_l0r = (const float*)d_in[8];
    const float* w_hh_l0r = (const float*)d_in[9];
    const float* b_ih_l0r = (const float*)d_in[10];
    const float* b_hh_l0r = (const float*)d_in[11];
    const float* w_ih_l1  = (const float*)d_in[12];
    const float* w_hh_l1  = (const float*)d_in[13];
    const float* b_ih_l1  = (const float*)d_in[14];
    const float* b_hh_l1  = (const float*)d_in[15];
    const float* w_ih_l1r = (const float*)d_in[16];
    const float* w_hh_l1r = (const float*)d_in[17];
    const float* b_ih_l1r = (const float*)d_in[18];
    const float* b_hh_l1r = (const float*)d_in[19];

    float* out = (float*)d_out;
    float* ws  = (float*)d_ws;

    const size_t HB = (size_t)4 * BATCH * HSZ;   // 131072
    float* h_buf0  = ws;
    float* h_buf1  = ws + HB;
    float* c_state = ws + 2 * HB;
    float* h1      = ws + 3 * HB;                // (T,B,1024)

    hipLaunchKernelGGL(init_state, dim3(512), dim3(256), 0, stream, h0, c0, h_buf0, c_state);

    // layer 0 (cells 0,1): input x, writes h1
    for (int s = 0; s < T_LEN; ++s) {
        float* hr = (s & 1) ? h_buf1 : h_buf0;
        float* hw = (s & 1) ? h_buf0 : h_buf1;
        hipLaunchKernelGGL((lstm_step<512>), dim3(128), dim3(256), 0, stream,
                           x, lengths,
                           w_ih_l0, w_hh_l0, b_ih_l0, b_hh_l0,
                           w_ih_l0r, w_hh_l0r, b_ih_l0r, b_hh_l0r,
                           hr, hw, c_state, h1, s);
    }

    // layer 1 (cells 2,3): input h1, writes out
    for (int s = 0; s < T_LEN; ++s) {
        float* hr = (s & 1) ? h_buf1 : h_buf0;
        float* hw = (s & 1) ? h_buf0 : h_buf1;
        hipLaunchKernelGGL((lstm_step<1024>), dim3(128), dim3(256), 0, stream,
                           h1, lengths,
                           w_ih_l1, w_hh_l1, b_ih_l1, b_hh_l1,
                           w_ih_l1r, w_hh_l1r, b_ih_l1r, b_hh_l1r,
                           hr, hw, c_state, out, s);
    }
}

// Round 2
// 10626.591 us; speedup vs baseline: 3.3406x; 3.3406x over previous
//
#include <hip/hip_runtime.h>
#include <hip/hip_bf16.h>
#include <math.h>

// Problem constants: T=256, B=64, I=512, H=512
#define T_LEN 256
#define BATCH 64
#define HSZ   512

typedef __bf16 bf16x8 __attribute__((ext_vector_type(8)));
typedef float  f32x4  __attribute__((ext_vector_type(4)));

// ---------- bf16 split helpers ----------
__device__ __forceinline__ unsigned short f2bf_rne(float f) {
    union { float f; unsigned int u; } c; c.f = f;
    unsigned int u = c.u;
    unsigned int r = (u + 0x7fffu + ((u >> 16) & 1u)) >> 16;
    return (unsigned short)r;
}
__device__ __forceinline__ float bf2f(unsigned short h) {
    union { unsigned int u; float f; } c; c.u = ((unsigned int)h) << 16;
    return c.f;
}
__device__ __forceinline__ void split_bf(float v, unsigned short& hi, unsigned short& lo) {
    hi = f2bf_rne(v);
    lo = f2bf_rne(v - bf2f(hi));
}

__device__ __forceinline__ float sigmoidf_(float x) {
    return 1.0f / (1.0f + __expf(-x));
}

// ---------- init ----------
__global__ void init_state(const float* __restrict__ h0, const float* __restrict__ c0,
                           float* __restrict__ h_buf0, float* __restrict__ c_state) {
    int i = blockIdx.x * blockDim.x + threadIdx.x;
    if (i < 4 * BATCH * HSZ) {
        h_buf0[i]  = h0[i];
        c_state[i] = c0[i];
    }
}

// ---------- weight packing ----------
// Packed layout (ushort): wp[cell][ft][kc][part][lane][e]
//   ft in [0,128): 16 packed rows each; packed row pr = u*4 + g  (u = pr>>2, g = pr&3)
//   kc: 32-k chunk index over KTOT = DIN+512 (Wih rows then Whh rows along k)
//   part: 0 = hi bf16, 1 = lo bf16
//   A-fragment mapping (16x16x32): lane l holds A[pr = ft*16 + (l&15)][k = kc*32 + (l>>4)*8 + e]
template<int DIN>
__global__ __launch_bounds__(256)
void pack_weights(const float* __restrict__ wih0, const float* __restrict__ whh0,
                  const float* __restrict__ wih1, const float* __restrict__ whh1,
                  unsigned short* __restrict__ wp) {
    constexpr int KTOT = DIN + 512;
    constexpr int KC = KTOT / 32;
    const size_t cell_sz = (size_t)128 * KC * 2 * 512;
    int t = blockIdx.x * blockDim.x + threadIdx.x;
    int total = 2 * 128 * KC * 64;
    if (t >= total) return;
    int lane = t & 63;
    int kc   = (t >> 6) % KC;
    int ft   = ((t >> 6) / KC) & 127;
    int cell = t / (64 * KC * 128);
    const float* wih = cell ? wih1 : wih0;
    const float* whh = cell ? whh1 : whh0;
    int pr = ft * 16 + (lane & 15);
    int u = pr >> 2, g = pr & 3;
    int row = g * 512 + u;
    int kbase = kc * 32 + (lane >> 4) * 8;
    union { unsigned short s[8]; uint4 v; } H, L;
#pragma unroll
    for (int e = 0; e < 8; ++e) {
        int k = kbase + e;
        float v = (k < DIN) ? wih[(size_t)row * DIN + k]
                            : whh[(size_t)row * 512 + (k - DIN)];
        split_bf(v, H.s[e], L.s[e]);
    }
    size_t base = (size_t)cell * cell_sz + (((size_t)ft * KC + kc) * 2) * 512 + (size_t)lane * 8;
    *reinterpret_cast<uint4*>(&wp[base])       = H.v;   // part 0 (hi)
    *reinterpret_cast<uint4*>(&wp[base + 512]) = L.v;   // part 1 (lo)
}

// ---------- one recurrent step (both directions of one layer) ----------
// Grid: 256 blocks = cd(2) x umt(64) x nh(2); 256 threads = 4 waves.
// Block: 32 packed rows (8 units x 4 gates) x 32 batches.
// Wave w: m-tile mt=w&1 (ft = umt*2+mt), n-tile nt=w>>1 (16 batches).
// Thread epilogue owns (u = umt*8 + (w&1)*4 + (l>>4), b = nh*32 + nt*16 + (l&15));
// acc regs 0..3 are gates i,f,g,o pre-activations (fp32).
template<int DIN>
__global__ __launch_bounds__(256)
void lstm_step_mfma(const float* __restrict__ zin,      // (T,B,DIN): x or h1
                    const int*   __restrict__ lengths,
                    const unsigned short* __restrict__ wp, // packed weights, layer base
                    const float* __restrict__ bih_f, const float* __restrict__ bhh_f,
                    const float* __restrict__ bih_b, const float* __restrict__ bhh_b,
                    const float* __restrict__ h_read,
                    float*       __restrict__ h_write,
                    float*       __restrict__ c_state,
                    float*       __restrict__ outp,     // (T,B,1024)
                    int s)
{
    constexpr int KTOT = DIN + 512;
    constexpr int KC   = KTOT / 32;
    constexpr int NCH  = KTOT / 256;
    constexpr int BASE_CELL = (DIN == 512) ? 0 : 2;

    const int bx  = blockIdx.x;
    const int cd  = bx & 1;
    const int umt = (bx >> 1) & 63;
    const int nh  = (bx >> 7) & 1;
    const int cell = BASE_CELL + cd;
    const int t   = cd ? (T_LEN - 1 - s) : s;

    const size_t cell_sz = (size_t)128 * KC * 2 * 512;
    const unsigned short* wpc = wp + (size_t)cd * cell_sz;

    const int tid = threadIdx.x;
    const int w = tid >> 6;
    const int l = tid & 63;

    __shared__ unsigned short zhi[32][264];   // padded: 264*2B = 528B row stride
    __shared__ unsigned short zlo[32][264];

    f32x4 acc = {0.f, 0.f, 0.f, 0.f};

    const int ft = umt * 2 + (w & 1);
    const int nt = w >> 1;
    const int bl_frag = nt * 16 + (l & 15);

    for (int ch = 0; ch < NCH; ++ch) {
        __syncthreads();
        // stage 256 k x 32 batches of z = [zin_t ; h_prev], split to hi/lo bf16
        {
            const int kglob0 = ch * 256;
#pragma unroll
            for (int i = 0; i < 8; ++i) {
                int f   = tid + i * 256;      // [0, 2048)
                int b_l = f >> 6;             // [0, 32)
                int k   = (f & 63) * 4;       // [0, 256) step 4
                int kg  = kglob0 + k;
                int b   = nh * 32 + b_l;
                float4 v;
                if (kg < DIN) {
                    v = *reinterpret_cast<const float4*>(&zin[((size_t)t * BATCH + b) * DIN + kg]);
                } else {
                    v = *reinterpret_cast<const float4*>(&h_read[((size_t)cell * BATCH + b) * HSZ + (kg - DIN)]);
                }
                unsigned short h0_, l0_, h1_, l1_, h2_, l2_, h3_, l3_;
                split_bf(v.x, h0_, l0_); split_bf(v.y, h1_, l1_);
                split_bf(v.z, h2_, l2_); split_bf(v.w, h3_, l3_);
                zhi[b_l][k + 0] = h0_; zhi[b_l][k + 1] = h1_; zhi[b_l][k + 2] = h2_; zhi[b_l][k + 3] = h3_;
                zlo[b_l][k + 0] = l0_; zlo[b_l][k + 1] = l1_; zlo[b_l][k + 2] = l2_; zlo[b_l][k + 3] = l3_;
            }
        }
        __syncthreads();

#pragma unroll
        for (int it = 0; it < 8; ++it) {
            int kc = ch * 8 + it;
            const unsigned short* wa = wpc + (((size_t)ft * KC + kc) * 2) * 512 + (size_t)l * 8;
            bf16x8 ahi = *reinterpret_cast<const bf16x8*>(wa);
            bf16x8 alo = *reinterpret_cast<const bf16x8*>(wa + 512);
            int koff = it * 32 + (l >> 4) * 8;
            bf16x8 bhi = *reinterpret_cast<const bf16x8*>(&zhi[bl_frag][koff]);
            bf16x8 blo = *reinterpret_cast<const bf16x8*>(&zlo[bl_frag][koff]);
            acc = __builtin_amdgcn_mfma_f32_16x16x32_bf16(ahi, bhi, acc, 0, 0, 0);
            acc = __builtin_amdgcn_mfma_f32_16x16x32_bf16(ahi, blo, acc, 0, 0, 0);
            acc = __builtin_amdgcn_mfma_f32_16x16x32_bf16(alo, bhi, acc, 0, 0, 0);
        }
    }

    // ---------- epilogue: pointwise cell update ----------
    const float* bih = cd ? bih_b : bih_f;
    const float* bhh = cd ? bhh_b : bhh_f;
    const int u = umt * 8 + (w & 1) * 4 + (l >> 4);
    const int b = nh * 32 + nt * 16 + (l & 15);

    float pre[4];
#pragma unroll
    for (int g = 0; g < 4; ++g) {
        int row = g * 512 + u;
        pre[g] = acc[g] + bih[row] + bhh[row];
    }
    const float gi = sigmoidf_(pre[0]);
    const float gf = sigmoidf_(pre[1]);
    const float gg = tanhf(pre[2]);
    const float go = sigmoidf_(pre[3]);

    const size_t idx = ((size_t)cell * BATCH + b) * HSZ + u;
    const float cprev = c_state[idx];
    const float hprev = h_read[idx];
    const float cy = gf * cprev + gi * gg;
    const float hy = go * tanhf(cy);
    const bool  m  = (t < lengths[b]);

    c_state[idx] = m ? cy : cprev;
    h_write[idx] = m ? hy : hprev;
    outp[((size_t)t * BATCH + b) * 1024 + cd * 512 + u] = m ? hy : 0.f;
}

extern "C" void kernel_launch(void* const* d_in, const int* in_sizes, int n_in,
                              void* d_out, int out_size, void* d_ws, size_t ws_size,
                              hipStream_t stream) {
    const float* x        = (const float*)d_in[0];
    const int*   lengths  = (const int*)d_in[1];
    const float* h0       = (const float*)d_in[2];
    const float* c0       = (const float*)d_in[3];
    const float* w_ih_l0  = (const float*)d_in[4];
    const float* w_hh_l0  = (const float*)d_in[5];
    const float* b_ih_l0  = (const float*)d_in[6];
    const float* b_hh_l0  = (const float*)d_in[7];
    const float* w_ih_l0r = (const float*)d_in[8];
    const float* w_hh_l0r = (const float*)d_in[9];
    const float* b_ih_l0r = (const float*)d_in[10];
    const float* b_hh_l0r = (const float*)d_in[11];
    const float* w_ih_l1  = (const float*)d_in[12];
    const float* w_hh_l1  = (const float*)d_in[13];
    const float* b_ih_l1  = (const float*)d_in[14];
    const float* b_hh_l1  = (const float*)d_in[15];
    const float* w_ih_l1r = (const float*)d_in[16];
    const float* w_hh_l1r = (const float*)d_in[17];
    const float* b_ih_l1r = (const float*)d_in[18];
    const float* b_hh_l1r = (const float*)d_in[19];

    float* out = (float*)d_out;
    float* ws  = (float*)d_ws;

    const size_t HB = (size_t)4 * BATCH * HSZ;     // 131072
    float* h_buf0  = ws;
    float* h_buf1  = ws + HB;
    float* c_state = ws + 2 * HB;
    float* h1      = ws + 3 * HB;                  // (T,B,1024) fp32
    unsigned short* wp   = (unsigned short*)(ws + 3 * HB + (size_t)T_LEN * BATCH * 1024);
    unsigned short* wp_l0 = wp;                                        // 2 cells * 128*32*2*512
    unsigned short* wp_l1 = wp + (size_t)2 * 128 * 32 * 2 * 512;       // 2 cells * 128*48*2*512

    hipLaunchKernelGGL(init_state, dim3(512), dim3(256), 0, stream, h0, c0, h_buf0, c_state);

    // pack weights (runs each launch; cheap, deterministic)
    hipLaunchKernelGGL((pack_weights<512>),  dim3(2048), dim3(256), 0, stream,
                       w_ih_l0, w_hh_l0, w_ih_l0r, w_hh_l0r, wp_l0);
    hipLaunchKernelGGL((pack_weights<1024>), dim3(3072), dim3(256), 0, stream,
                       w_ih_l1, w_hh_l1, w_ih_l1r, w_hh_l1r, wp_l1);

    // layer 0 (cells 0,1): input x, writes h1
    for (int s = 0; s < T_LEN; ++s) {
        float* hr = (s & 1) ? h_buf1 : h_buf0;
        float* hw = (s & 1) ? h_buf0 : h_buf1;
        hipLaunchKernelGGL((lstm_step_mfma<512>), dim3(256), dim3(256), 0, stream,
                           x, lengths, wp_l0,
                           b_ih_l0, b_hh_l0, b_ih_l0r, b_hh_l0r,
                           hr, hw, c_state, h1, s);
    }

    // layer 1 (cells 2,3): input h1, writes out
    for (int s = 0; s < T_LEN; ++s) {
        float* hr = (s & 1) ? h_buf1 : h_buf0;
        float* hw = (s & 1) ? h_buf0 : h_buf1;
        hipLaunchKernelGGL((lstm_step_mfma<1024>), dim3(256), dim3(256), 0, stream,
                           h1, lengths, wp_l1,
                           b_ih_l1, b_hh_l1, b_ih_l1r, b_hh_l1r,
                           hr, hw, c_state, out, s);
    }
}